// Round 9
// baseline (898.639 us; speedup 1.0000x reference)
//
#include <hip/hip_runtime.h>

// GraphSAGE 3-layer forward. R9:
//   * Bt/Abf/Hb stored SLICE-MAJOR (16-col slices); agg kernels pin one slice
//     per XCD via blockIdx&7 (&3) -> per-XCD L2 working set 3.2MB (fits 4MB).
//     Wave = 1 node, 8 edges x 8 lanes (32B slice row), shfl_xor reduce.
//     esrc/A via nontemporal loads, Hb via nontemporal store (keep L2 for Bt).
//   * CSR build: pscatter writes BLOCK-MAJOR pb (private contiguous region,
//     no cross-block cacheline sharing) + lofs[(bucket,blk)] + non-returning
//     atomic bucket totals. phist + big scans eliminated.
// Pipeline: memset(btot); pack; pscatter+gemm0(fused); bucket_place;
//           {agg128; gemm; agg128; gemm; agg64}.

#define NN 100000
#define NE 1600000
#define BSH 7               // 128 dst-nodes per bucket
#define BND 128
#define NB  782             // ceil(100000/128)
#define NBLKS 256           // partition blocks (NE = 256*6250 exactly)
#define EPB (NE / NBLKS)    // 6250
#define GEMM_BLOCKS 1563    // ceil((NN/16)/4)

typedef __attribute__((ext_vector_type(8))) short short8;
typedef __attribute__((ext_vector_type(4))) float f32x4;
typedef unsigned int uint;
typedef unsigned short ushort;

__device__ inline ushort f2bf(float f) {
    uint u = __float_as_uint(f);
    u += 0x7FFFu + ((u >> 16) & 1u);
    return (ushort)(u >> 16);
}
__device__ inline float bf_lo(uint w) { return __uint_as_float(w << 16); }
__device__ inline float bf_hi(uint w) { return __uint_as_float(w & 0xFFFF0000u); }

// ---------------- weight pack (standalone; must precede gemm0) ----------------
__global__ __launch_bounds__(256) void pack_k(
    const float* __restrict__ ws0, const float* __restrict__ wn0, ushort* __restrict__ wf0,
    const float* __restrict__ ws1, const float* __restrict__ wn1, ushort* __restrict__ wf1,
    const float* __restrict__ ws2, const float* __restrict__ wn2, ushort* __restrict__ wf2)
{
    const int b = blockIdx.x;
    const int t = threadIdx.x;
    const float *ws, *wn; ushort* wf; int ncs, idx;
    if (b < 16)      { ws = ws0; wn = wn0; wf = wf0; ncs = 128; idx = b * 256 + t; }
    else if (b < 32) { ws = ws1; wn = wn1; wf = wf1; ncs = 128; idx = (b - 16) * 256 + t; }
    else             { ws = ws2; wn = wn2; wf = wf2; ncs = 64;  idx = (b - 32) * 256 + t; }
    const int total = (2 * ncs / 16) * 4 * 64;
    if (idx >= total) return;
    const int l = idx & 63;
    const int f = idx >> 6;
    const int kt = f & 3;
    const int ct = f >> 2;
    const int n = ct * 16 + (l & 15);
    const int k0 = kt * 32 + (l >> 4) * 8;
    uint w[4];
    #pragma unroll
    for (int p = 0; p < 4; ++p) {
        const int k = k0 + p * 2;
        float v0, v1;
        if (n < ncs) { v0 = ws[k * ncs + n];         v1 = ws[(k + 1) * ncs + n]; }
        else         { v0 = wn[k * ncs + (n - ncs)]; v1 = wn[(k + 1) * ncs + (n - ncs)]; }
        w[p] = (uint)f2bf(v0) | ((uint)f2bf(v1) << 16);
    }
    uint4 o; o.x = w[0]; o.y = w[1]; o.z = w[2]; o.w = w[3];
    ((uint4*)wf)[idx] = o;
}

// ---------------- fused MFMA GEMM body ----------------
// Hb/Abf/Bt are SLICE-MAJOR: elem(slice, node, j) at slice*NN*16 + node*16 + j.
// XF32: layer-0 reads row-major fp32 x. ABF=false: layer-2 writes row-major fp32.
template<int NCS, int NCN, bool XF32, bool ABF>
__device__ void gemm_body(int bid, int tid,
    const void* __restrict__ Hv, const ushort* __restrict__ Wf,
    const float* __restrict__ bias, void* __restrict__ Av, ushort* __restrict__ Bt)
{
    constexpr int NCT = (NCS + NCN) / 16;
    const int g = (bid * 256 + tid) >> 6;
    if (g >= NN / 16) return;
    const int lane = tid & 63;
    const int m = lane & 15;
    const int q = lane >> 4;
    const int node = g * 16 + m;

    short8 af[4];
    if (XF32) {
        const float* hp = (const float*)Hv + (size_t)node * 128;
        #pragma unroll
        for (int kt = 0; kt < 4; ++kt) {
            const float4 f0 = *(const float4*)(hp + kt * 32 + q * 8);
            const float4 f1 = *(const float4*)(hp + kt * 32 + q * 8 + 4);
            short8 v;
            v[0] = (short)f2bf(f0.x); v[1] = (short)f2bf(f0.y);
            v[2] = (short)f2bf(f0.z); v[3] = (short)f2bf(f0.w);
            v[4] = (short)f2bf(f1.x); v[5] = (short)f2bf(f1.y);
            v[6] = (short)f2bf(f1.z); v[7] = (short)f2bf(f1.w);
            af[kt] = v;
        }
    } else {
        const ushort* Hs = (const ushort*)Hv;
        #pragma unroll
        for (int kt = 0; kt < 4; ++kt) {
            const int sl = 2 * kt + (q >> 1);             // k0 = kt*32+q*8 -> slice
            af[kt] = *(const short8*)(Hs + (size_t)sl * NN * 16 + (size_t)node * 16 + 8 * (q & 1));
        }
    }

    f32x4 acc[NCT];
    #pragma unroll
    for (int i = 0; i < NCT; ++i) acc[i] = (f32x4){0.f, 0.f, 0.f, 0.f};

    const short8* wp = (const short8*)Wf;
    #pragma unroll
    for (int ct = 0; ct < NCT; ++ct) {
        #pragma unroll
        for (int kt = 0; kt < 4; ++kt) {
            const short8 bf = wp[(ct * 4 + kt) * 64 + lane];
            acc[ct] = __builtin_amdgcn_mfma_f32_16x16x32_bf16(af[kt], bf, acc[ct], 0, 0, 0);
        }
    }

    const int r0 = g * 16 + q * 4;
    #pragma unroll
    for (int ct = 0; ct < NCS / 16; ++ct) {
        const int c = ct * 16 + m;
        const float bv = bias[c];
        #pragma unroll
        for (int r = 0; r < 4; ++r) {
            const float v = acc[ct][r] + bv;
            if (ABF) ((ushort*)Av)[(size_t)ct * NN * 16 + (size_t)(r0 + r) * 16 + m] = f2bf(v);
            else     ((float*) Av)[(size_t)(r0 + r) * NCS + c] = v;
        }
    }
    #pragma unroll
    for (int ct = NCS / 16; ct < NCT; ++ct) {
        const int s = ct - NCS / 16;
        #pragma unroll
        for (int r = 0; r < 4; ++r)
            Bt[(size_t)s * NN * 16 + (size_t)(r0 + r) * 16 + m] = f2bf(acc[ct][r]);
    }
}

template<int NCS, int NCN, bool XF32, bool ABF>
__global__ __launch_bounds__(256) void gemm_mfma_k(
    const void* __restrict__ Hv, const ushort* __restrict__ Wf,
    const float* __restrict__ bias, void* __restrict__ Av, ushort* __restrict__ Bt)
{
    gemm_body<NCS, NCN, XF32, ABF>(blockIdx.x, threadIdx.x, Hv, Wf, bias, Av, Bt);
}

// ---------------- pscatter (block-major pb) + fused layer-0 GEMM ----------------
// blocks [0,NBLKS): local hist + LDS scan; write pb into private region
// [blk*EPB, (blk+1)*EPB); write lofs[(bucket,blk)]; atomicAdd bucket totals.
// blocks [NBLKS, NBLKS+GEMM_BLOCKS): gemm0 (x -> Abf,Bt).
__global__ __launch_bounds__(256) void pscatter_gemm0_k(
    const int* __restrict__ src, const int* __restrict__ dst,
    int* __restrict__ pb, int* __restrict__ lofs, int* __restrict__ btot,
    const float* __restrict__ x, const ushort* __restrict__ wf0,
    const float* __restrict__ b0, ushort* __restrict__ Abf, ushort* __restrict__ Bt)
{
    __shared__ int h[NB];
    __shared__ int wc[NB];
    __shared__ int tsum[256];
    const int t = threadIdx.x;
    if (blockIdx.x >= NBLKS) {
        gemm_body<128, 128, true, true>(blockIdx.x - NBLKS, t, x, wf0, b0, Abf, Bt);
        return;
    }
    const int blk = blockIdx.x;
    const int e0 = blk * EPB;
    for (int i = t; i < NB; i += 256) h[i] = 0;
    __syncthreads();
    for (int e = e0 + t; e < e0 + EPB; e += 256)
        atomicAdd(&h[dst[e] >> BSH], 1);
    __syncthreads();
    // LDS exclusive scan of h[NB] (4 entries/thread + Hillis-Steele on 256 sums)
    int v[4];
    const int base4 = t * 4;
    #pragma unroll
    for (int i = 0; i < 4; ++i) {
        const int idx = base4 + i;
        v[i] = (idx < NB) ? h[idx] : 0;
    }
    const int s = v[0] + v[1] + v[2] + v[3];
    tsum[t] = s;
    __syncthreads();
    #pragma unroll
    for (int off = 1; off < 256; off <<= 1) {
        const int cur = tsum[t];
        const int y = (t >= off) ? tsum[t - off] : 0;
        __syncthreads();
        tsum[t] = cur + y;
        __syncthreads();
    }
    int run = tsum[t] - s;
    #pragma unroll
    for (int i = 0; i < 4; ++i) {
        const int idx = base4 + i;
        if (idx < NB) {
            wc[idx] = run;
            lofs[idx * NBLKS + blk] = run;
            if (v[i]) atomicAdd(&btot[idx], v[i]);   // non-returning: no serialization
        }
        run += v[i];
    }
    __syncthreads();
    for (int e = e0 + t; e < e0 + EPB; e += 256) {
        const int d = dst[e];
        const int pos = e0 + atomicAdd(&wc[d >> BSH], 1);
        pb[pos] = (src[e] << BSH) | (d & (BND - 1));
    }
}

// ---------------- bucket_place: one block per bucket ----------------
// s0 = prefix(btot)<b via masked reduce; runs located by lofs; emits row[], esrc.
__global__ __launch_bounds__(256) void bucket_place_k(
    const int* __restrict__ btot, const int* __restrict__ lofs,
    const int* __restrict__ pb, int* __restrict__ row, int* __restrict__ esrc)
{
    __shared__ int cnt[BND], wc[BND], excl[BND], scan[BND];
    __shared__ int red[256];
    const int b = blockIdx.x;
    const int t = threadIdx.x;
    // s0 = sum of btot[idx] for idx < b
    int part = 0;
    #pragma unroll
    for (int i = 0; i < 4; ++i) {
        const int idx = t * 4 + i;
        if (idx < b && idx < NB) part += btot[idx];
    }
    red[t] = part;
    if (t < BND) { cnt[t] = 0; wc[t] = 0; }
    __syncthreads();
    for (int off = 128; off > 0; off >>= 1) {
        if (t < off) red[t] += red[t + off];
        __syncthreads();
    }
    const int s0 = red[0];
    // this thread's run (partition block t)
    const int lo = lofs[b * NBLKS + t];
    const int lcount = ((b + 1 < NB) ? lofs[(b + 1) * NBLKS + t] : EPB) - lo;
    const int lstart = t * EPB + lo;
    for (int k = 0; k < lcount; ++k)
        atomicAdd(&cnt[pb[lstart + k] & (BND - 1)], 1);
    __syncthreads();
    if (t < BND) scan[t] = cnt[t];
    __syncthreads();
    for (int off = 1; off < BND; off <<= 1) {
        int nv = 0;
        if (t < BND) {
            nv = scan[t];
            if (t >= off) nv += scan[t - off];
        }
        __syncthreads();
        if (t < BND) scan[t] = nv;
        __syncthreads();
    }
    if (t < BND) {
        const int ex = scan[t] - cnt[t];
        excl[t] = ex;
        const int node = b * BND + t;
        if (node <= NN) row[node] = s0 + ex;   // node==NN -> row[NN]=NE
    }
    __syncthreads();
    for (int k = 0; k < lcount; ++k) {
        const int p = pb[lstart + k];
        const int dl = p & (BND - 1);
        const int pos = s0 + excl[dl] + atomicAdd(&wc[dl], 1);
        esrc[pos] = p >> BSH;
    }
}

// ---------------- aggregation (XCD-sliced) ----------------
// agg128: 8 slices, slice = blockIdx&7 (one slice per XCD). Wave = 1 node;
// lane = g*8+f: g = edge slot (8 parallel), f = feature pair (32B slice row).
__global__ __launch_bounds__(256) void agg128_k(
    const int* __restrict__ row, const int* __restrict__ esrc,
    const uint* __restrict__ BtU, const uint* __restrict__ AbfU, uint* __restrict__ HbU)
{
    const int slice = blockIdx.x & 7;
    const int node = (blockIdx.x >> 3) * 4 + (threadIdx.x >> 6);
    const int lane = threadIdx.x & 63;
    const int f = lane & 7;
    const int g = lane >> 3;
    const int e0 = row[node];
    const int e1 = row[node + 1];
    const uint* B = BtU + (size_t)slice * NN * 8;
    float a0 = 0.f, a1 = 0.f;
    int e = e0 + g;
    for (; e + 8 < e1; e += 16) {
        const int s0 = __builtin_nontemporal_load(esrc + e);
        const int s1 = __builtin_nontemporal_load(esrc + e + 8);
        const uint v0 = B[(size_t)s0 * 8 + f];
        const uint v1 = B[(size_t)s1 * 8 + f];
        a0 += bf_lo(v0) + bf_lo(v1);
        a1 += bf_hi(v0) + bf_hi(v1);
    }
    if (e < e1) {
        const int s0 = __builtin_nontemporal_load(esrc + e);
        const uint v0 = B[(size_t)s0 * 8 + f];
        a0 += bf_lo(v0);
        a1 += bf_hi(v0);
    }
    a0 += __shfl_xor(a0, 8);  a1 += __shfl_xor(a1, 8);
    a0 += __shfl_xor(a0, 16); a1 += __shfl_xor(a1, 16);
    a0 += __shfl_xor(a0, 32); a1 += __shfl_xor(a1, 32);
    if (g == 0) {
        const int deg = e1 - e0;
        const float invd = (deg > 0) ? 1.0f / (float)deg : 0.0f;
        const uint aw = __builtin_nontemporal_load(AbfU + (size_t)slice * NN * 8 + (size_t)node * 8 + f);
        const float v0 = fmaxf(bf_lo(aw) + a0 * invd, 0.f);
        const float v1 = fmaxf(bf_hi(aw) + a1 * invd, 0.f);
        __builtin_nontemporal_store((uint)f2bf(v0) | ((uint)f2bf(v1) << 16),
                                    HbU + (size_t)slice * NN * 8 + (size_t)node * 8 + f);
    }
}

// agg64: 4 slices, slice = blockIdx&3 (XCDs x and x+4 share slice x&3 — each
// XCD still touches exactly one 3.2MB slice). out fp32 row-major: slice writes
// one 64B line per node. out[node] += mean(Bt2[src]), no relu.
__global__ __launch_bounds__(256) void agg64_k(
    const int* __restrict__ row, const int* __restrict__ esrc,
    const uint* __restrict__ BtU, float* __restrict__ out)
{
    const int slice = blockIdx.x & 3;
    const int node = (blockIdx.x >> 2) * 4 + (threadIdx.x >> 6);
    const int lane = threadIdx.x & 63;
    const int f = lane & 7;
    const int g = lane >> 3;
    const int e0 = row[node];
    const int e1 = row[node + 1];
    const uint* B = BtU + (size_t)slice * NN * 8;
    float a0 = 0.f, a1 = 0.f;
    int e = e0 + g;
    for (; e + 8 < e1; e += 16) {
        const int s0 = __builtin_nontemporal_load(esrc + e);
        const int s1 = __builtin_nontemporal_load(esrc + e + 8);
        const uint v0 = B[(size_t)s0 * 8 + f];
        const uint v1 = B[(size_t)s1 * 8 + f];
        a0 += bf_lo(v0) + bf_lo(v1);
        a1 += bf_hi(v0) + bf_hi(v1);
    }
    if (e < e1) {
        const int s0 = __builtin_nontemporal_load(esrc + e);
        const uint v0 = B[(size_t)s0 * 8 + f];
        a0 += bf_lo(v0);
        a1 += bf_hi(v0);
    }
    a0 += __shfl_xor(a0, 8);  a1 += __shfl_xor(a1, 8);
    a0 += __shfl_xor(a0, 16); a1 += __shfl_xor(a1, 16);
    a0 += __shfl_xor(a0, 32); a1 += __shfl_xor(a1, 32);
    if (g == 0) {
        const int deg = e1 - e0;
        const float invd = (deg > 0) ? 1.0f / (float)deg : 0.0f;
        float2* op = (float2*)(out + (size_t)node * 64 + slice * 16 + f * 2);
        float2 o = *op;
        o.x += a0 * invd;
        o.y += a1 * invd;
        *op = o;
    }
}

// ---------------- fp32 fallback path (small workspace) ----------------
__device__ inline float4 relu4f(float4 v) {
    v.x = fmaxf(v.x, 0.f); v.y = fmaxf(v.y, 0.f);
    v.z = fmaxf(v.z, 0.f); v.w = fmaxf(v.w, 0.f);
    return v;
}
template<int NCOL, bool RELU_IN, bool BIAS>
__global__ __launch_bounds__(256) void gemm_k(
    const float* in, const float* __restrict__ W,
    const float* __restrict__ bias, float* out)
{
    constexpr int K = 128;
    constexpr int QUADS = NCOL / 4;
    constexpr int G = 256 / QUADS;
    constexpr int RPT = 32 / G;
    __shared__ float Wlds[K * NCOL];
    {
        const float4* Wg = reinterpret_cast<const float4*>(W);
        float4* Wl = reinterpret_cast<float4*>(Wlds);
        #pragma unroll
        for (int i = 0; i < K * NCOL / 4 / 256; ++i)
            Wl[threadIdx.x + i * 256] = Wg[threadIdx.x + i * 256];
    }
    __syncthreads();
    const int tx = threadIdx.x % QUADS;
    const int ty = threadIdx.x / QUADS;
    const int row0 = blockIdx.x * 32;
    const float* rp[RPT];
    #pragma unroll
    for (int i = 0; i < RPT; ++i) rp[i] = in + (size_t)(row0 + ty + i * G) * K;
    float acc[RPT][4];
    #pragma unroll
    for (int i = 0; i < RPT; ++i) acc[i][0] = acc[i][1] = acc[i][2] = acc[i][3] = 0.f;
    #pragma unroll 2
    for (int kc = 0; kc < K; kc += 4) {
        float4 h4[RPT];
        #pragma unroll
        for (int i = 0; i < RPT; ++i) {
            h4[i] = *reinterpret_cast<const float4*>(rp[i] + kc);
            if (RELU_IN) h4[i] = relu4f(h4[i]);
        }
        #pragma unroll
        for (int kk = 0; kk < 4; ++kk) {
            const float4 w4 = *reinterpret_cast<const float4*>(&Wlds[(kc + kk) * NCOL + tx * 4]);
            #pragma unroll
            for (int i = 0; i < RPT; ++i) {
                const float hv = (&h4[i].x)[kk];
                acc[i][0] = fmaf(hv, w4.x, acc[i][0]);
                acc[i][1] = fmaf(hv, w4.y, acc[i][1]);
                acc[i][2] = fmaf(hv, w4.z, acc[i][2]);
                acc[i][3] = fmaf(hv, w4.w, acc[i][3]);
            }
        }
    }
    float4 b4 = make_float4(0.f, 0.f, 0.f, 0.f);
    if (BIAS) b4 = *reinterpret_cast<const float4*>(&bias[tx * 4]);
    #pragma unroll
    for (int i = 0; i < RPT; ++i) {
        const int r = row0 + ty + i * G;
        float4 o;
        o.x = acc[i][0] + b4.x; o.y = acc[i][1] + b4.y;
        o.z = acc[i][2] + b4.z; o.w = acc[i][3] + b4.w;
        *reinterpret_cast<float4*>(&out[(size_t)r * NCOL + tx * 4]) = o;
    }
}
__global__ void deg_k(const int* __restrict__ dst, float* __restrict__ deg, int E) {
    const int i = blockIdx.x * blockDim.x + threadIdx.x;
    if (i < E) atomicAdd(&deg[dst[i]], 1.0f);
}
__global__ void inv_k(float* deg, int n) {
    const int i = blockIdx.x * blockDim.x + threadIdx.x;
    if (i < n) deg[i] = 1.0f / fmaxf(deg[i], 1.0f);
}
__global__ __launch_bounds__(256) void scatter128_k(
    const int* __restrict__ src, const int* __restrict__ dst,
    const float* __restrict__ inv, const float* __restrict__ B, float* A, int E) {
    const int lane = threadIdx.x & 63;
    int w = (blockIdx.x * 256 + threadIdx.x) >> 6;
    const int nw = (gridDim.x * 256) >> 6;
    for (int e = w; e < E; e += nw) {
        const int s = src[e], d = dst[e];
        const float sc = inv[d];
        const float2 v = *reinterpret_cast<const float2*>(&B[(size_t)s * 128 + lane * 2]);
        atomicAdd(&A[(size_t)d * 128 + lane * 2    ], v.x * sc);
        atomicAdd(&A[(size_t)d * 128 + lane * 2 + 1], v.y * sc);
    }
}
__global__ __launch_bounds__(256) void scatter64_k(
    const int* __restrict__ src, const int* __restrict__ dst,
    const float* __restrict__ inv, const float* __restrict__ B, float* A, int E) {
    const int lane = threadIdx.x & 63;
    int w = (blockIdx.x * 256 + threadIdx.x) >> 6;
    const int nw = (gridDim.x * 256) >> 6;
    for (int e = w; e < E; e += nw) {
        const int s = src[e], d = dst[e];
        atomicAdd(&A[(size_t)d * 64 + lane], B[(size_t)s * 64 + lane] * inv[d]);
    }
}

extern "C" void kernel_launch(void* const* d_in, const int* in_sizes, int n_in,
                              void* d_out, int out_size, void* d_ws, size_t ws_size,
                              hipStream_t stream) {
    const float* x   = (const float*)d_in[0];
    const int*   src = (const int*)  d_in[1];
    const int*   dst = (const int*)  d_in[2];
    const float* ws0 = (const float*)d_in[3];
    const float* wn0 = (const float*)d_in[4];
    const float* b0  = (const float*)d_in[5];
    const float* ws1 = (const float*)d_in[6];
    const float* wn1 = (const float*)d_in[7];
    const float* b1  = (const float*)d_in[8];
    const float* ws2 = (const float*)d_in[9];
    const float* wn2 = (const float*)d_in[10];
    const float* b2  = (const float*)d_in[11];
    float* out = (float*)d_out;

    // workspace layout (byte offsets, no aliasing)
    const size_t O_BTOT = 4096;       // NB*4 = 3128
    const size_t O_ROW  = 16384;      // (NN+1)*4
    const size_t O_WF0  = 417792;     // 65536
    const size_t O_WF1  = 483328;     // 65536
    const size_t O_WF2  = 548864;     // 32768
    const size_t O_ESRC = 581632;     // 6,400,000
    const size_t O_PB   = 6983680;    // 6,400,000
    const size_t O_LOFS = 13383680;   // 800,768
    const size_t O_A    = 14185472;   // 25,600,000 (bf16, slice-major)
    const size_t O_BT   = 39785472;   // 25,600,000
    const size_t O_HB   = 65385472;   // 25,600,000
    const size_t NEED   = 90985472;

    if (ws_size >= NEED) {
        int*    btot = (int*)   ((char*)d_ws + O_BTOT);
        int*    row  = (int*)   ((char*)d_ws + O_ROW);
        ushort* wf0  = (ushort*)((char*)d_ws + O_WF0);
        ushort* wf1  = (ushort*)((char*)d_ws + O_WF1);
        ushort* wf2  = (ushort*)((char*)d_ws + O_WF2);
        int*    esrc = (int*)   ((char*)d_ws + O_ESRC);
        int*    pb   = (int*)   ((char*)d_ws + O_PB);
        int*    lofs = (int*)   ((char*)d_ws + O_LOFS);
        ushort* Abf  = (ushort*)((char*)d_ws + O_A);
        ushort* Bt   = (ushort*)((char*)d_ws + O_BT);
        ushort* Hb   = (ushort*)((char*)d_ws + O_HB);

        hipMemsetAsync(btot, 0, NB * sizeof(int), stream);
        pack_k<<<40, 256, 0, stream>>>(ws0, wn0, wf0, ws1, wn1, wf1, ws2, wn2, wf2);
        pscatter_gemm0_k<<<NBLKS + GEMM_BLOCKS, 256, 0, stream>>>(
            src, dst, pb, lofs, btot, x, wf0, b0, Abf, Bt);
        bucket_place_k<<<NB, 256, 0, stream>>>(btot, lofs, pb, row, esrc);

        const int AGG128_GRID = 8 * (NN / 4);   // 200000 (slice x node-group)
        const int AGG64_GRID  = 4 * (NN / 4);   // 100000

        // layer 0 (gemm0 done in fused launch)
        agg128_k<<<AGG128_GRID, 256, 0, stream>>>(row, esrc, (uint*)Bt, (uint*)Abf, (uint*)Hb);
        // layer 1
        gemm_mfma_k<128, 128, false, true ><<<GEMM_BLOCKS, 256, 0, stream>>>(Hb, wf1, b1, Abf, Bt);
        agg128_k<<<AGG128_GRID, 256, 0, stream>>>(row, esrc, (uint*)Bt, (uint*)Abf, (uint*)Hb);
        // layer 2 (self fp32 straight to d_out; then sliced mean add)
        gemm_mfma_k<64, 64, false, false><<<GEMM_BLOCKS, 256, 0, stream>>>(Hb, wf2, b2, out, Bt);
        agg64_k<<<AGG64_GRID, 256, 0, stream>>>(row, esrc, (uint*)Bt, out);
    } else {
        // fp32 atomic fallback
        float* inv = (float*)d_ws;
        float* H0  = (float*)((char*)d_ws + (1u << 20));
        float* Bf  = H0 + (size_t)NN * 128;
        const int GB = NN / 32;
        const int SC_BLOCKS = 4096;
        hipMemsetAsync(inv, 0, NN * sizeof(float), stream);
        deg_k<<<(NE + 255) / 256, 256, 0, stream>>>(dst, inv, NE);
        inv_k<<<(NN + 255) / 256, 256, 0, stream>>>(inv, NN);
        gemm_k<128, false, false><<<GB, 256, 0, stream>>>(x, wn0, nullptr, Bf);
        gemm_k<128, false, true ><<<GB, 256, 0, stream>>>(x, ws0, b0, H0);
        scatter128_k<<<SC_BLOCKS, 256, 0, stream>>>(src, dst, inv, Bf, H0, NE);
        gemm_k<128, true, false><<<GB, 256, 0, stream>>>(H0, wn1, nullptr, Bf);
        gemm_k<128, true, true ><<<GB, 256, 0, stream>>>(H0, ws1, b1, H0);
        scatter128_k<<<SC_BLOCKS, 256, 0, stream>>>(src, dst, inv, Bf, H0, NE);
        gemm_k<64, true, false><<<GB, 256, 0, stream>>>(H0, wn2, nullptr, Bf);
        gemm_k<64, true, true ><<<GB, 256, 0, stream>>>(H0, ws2, b2, out);
        scatter64_k<<<SC_BLOCKS, 256, 0, stream>>>(src, dst, inv, Bf, out, NE);
    }
}

// Round 10
// 415.987 us; speedup vs baseline: 2.1603x; 2.1603x over previous
//
#include <hip/hip_runtime.h>

// GraphSAGE 3-layer forward. R10 = R8's proven row-major agg/gemm kernels
// + R9's improved CSR build (block-major pb: private contiguous writes, no
// phist/global scans, non-returning atomic bucket totals).
// R9 lesson: slice-major gather (32B rows, 1 node/wave) was latency-bound
// (264us vs 61us) despite 3.6x lower FETCH — keep >=256B/edge rows and
// multi-node waves.
// Pipeline: memset(btot); pack; pscatter+gemm0(fused); bucket_place;
//           {agg128; gemm1; agg128; gemm2; agg64}.

#define NN 100000
#define NE 1600000
#define BSH 7               // 128 dst-nodes per bucket
#define BND 128
#define NB  782             // ceil(100000/128)
#define NBLKS 256           // partition blocks (NE = 256*6250 exactly)
#define EPB (NE / NBLKS)    // 6250
#define GEMM_BLOCKS 1563    // ceil((NN/16)/4)

typedef __attribute__((ext_vector_type(8))) short short8;
typedef __attribute__((ext_vector_type(4))) float f32x4;
typedef unsigned int uint;
typedef unsigned short ushort;

__device__ inline ushort f2bf(float f) {
    uint u = __float_as_uint(f);
    u += 0x7FFFu + ((u >> 16) & 1u);
    return (ushort)(u >> 16);
}
__device__ inline float bf_lo(uint w) { return __uint_as_float(w << 16); }
__device__ inline float bf_hi(uint w) { return __uint_as_float(w & 0xFFFF0000u); }

// ---------------- weight pack (standalone; must precede gemm0) ----------------
__global__ __launch_bounds__(256) void pack_k(
    const float* __restrict__ ws0, const float* __restrict__ wn0, ushort* __restrict__ wf0,
    const float* __restrict__ ws1, const float* __restrict__ wn1, ushort* __restrict__ wf1,
    const float* __restrict__ ws2, const float* __restrict__ wn2, ushort* __restrict__ wf2)
{
    const int b = blockIdx.x;
    const int t = threadIdx.x;
    const float *ws, *wn; ushort* wf; int ncs, idx;
    if (b < 16)      { ws = ws0; wn = wn0; wf = wf0; ncs = 128; idx = b * 256 + t; }
    else if (b < 32) { ws = ws1; wn = wn1; wf = wf1; ncs = 128; idx = (b - 16) * 256 + t; }
    else             { ws = ws2; wn = wn2; wf = wf2; ncs = 64;  idx = (b - 32) * 256 + t; }
    const int total = (2 * ncs / 16) * 4 * 64;
    if (idx >= total) return;
    const int l = idx & 63;
    const int f = idx >> 6;
    const int kt = f & 3;
    const int ct = f >> 2;
    const int n = ct * 16 + (l & 15);
    const int k0 = kt * 32 + (l >> 4) * 8;
    uint w[4];
    #pragma unroll
    for (int p = 0; p < 4; ++p) {
        const int k = k0 + p * 2;
        float v0, v1;
        if (n < ncs) { v0 = ws[k * ncs + n];         v1 = ws[(k + 1) * ncs + n]; }
        else         { v0 = wn[k * ncs + (n - ncs)]; v1 = wn[(k + 1) * ncs + (n - ncs)]; }
        w[p] = (uint)f2bf(v0) | ((uint)f2bf(v1) << 16);
    }
    uint4 o; o.x = w[0]; o.y = w[1]; o.z = w[2]; o.w = w[3];
    ((uint4*)wf)[idx] = o;
}

// ---------------- fused MFMA GEMM body (row-major, R8) ----------------
template<int NCS, int NCN, bool XF32, bool ABF>
__device__ void gemm_body(int bid, int tid,
    const void* __restrict__ Hv, const ushort* __restrict__ Wf,
    const float* __restrict__ bias, void* __restrict__ Av, ushort* __restrict__ Bt)
{
    constexpr int NCT = (NCS + NCN) / 16;
    const int g = (bid * 256 + tid) >> 6;
    if (g >= NN / 16) return;
    const int lane = tid & 63;
    const int m = lane & 15;
    const int q = lane >> 4;

    short8 af[4];
    if (XF32) {
        const float* hp = (const float*)Hv + (size_t)(g * 16 + m) * 128;
        #pragma unroll
        for (int kt = 0; kt < 4; ++kt) {
            const float4 f0 = *(const float4*)(hp + kt * 32 + q * 8);
            const float4 f1 = *(const float4*)(hp + kt * 32 + q * 8 + 4);
            short8 v;
            v[0] = (short)f2bf(f0.x); v[1] = (short)f2bf(f0.y);
            v[2] = (short)f2bf(f0.z); v[3] = (short)f2bf(f0.w);
            v[4] = (short)f2bf(f1.x); v[5] = (short)f2bf(f1.y);
            v[6] = (short)f2bf(f1.z); v[7] = (short)f2bf(f1.w);
            af[kt] = v;
        }
    } else {
        const short8* hp = (const short8*)((const ushort*)Hv + (size_t)(g * 16 + m) * 128);
        #pragma unroll
        for (int kt = 0; kt < 4; ++kt) af[kt] = hp[kt * 4 + q];
    }

    f32x4 acc[NCT];
    #pragma unroll
    for (int i = 0; i < NCT; ++i) acc[i] = (f32x4){0.f, 0.f, 0.f, 0.f};

    const short8* wp = (const short8*)Wf;
    #pragma unroll
    for (int ct = 0; ct < NCT; ++ct) {
        #pragma unroll
        for (int kt = 0; kt < 4; ++kt) {
            const short8 bf = wp[(ct * 4 + kt) * 64 + lane];
            acc[ct] = __builtin_amdgcn_mfma_f32_16x16x32_bf16(af[kt], bf, acc[ct], 0, 0, 0);
        }
    }

    const int r0 = g * 16 + q * 4;
    #pragma unroll
    for (int ct = 0; ct < NCS / 16; ++ct) {
        const int c = ct * 16 + m;
        const float bv = bias[c];
        #pragma unroll
        for (int r = 0; r < 4; ++r) {
            const float v = acc[ct][r] + bv;
            if (ABF) ((ushort*)Av)[(size_t)(r0 + r) * NCS + c] = f2bf(v);
            else     ((float*) Av)[(size_t)(r0 + r) * NCS + c] = v;
        }
    }
    #pragma unroll
    for (int ct = NCS / 16; ct < NCT; ++ct) {
        const int c = ct * 16 + m - NCS;
        #pragma unroll
        for (int r = 0; r < 4; ++r)
            Bt[(size_t)(r0 + r) * NCN + c] = f2bf(acc[ct][r]);
    }
}

template<int NCS, int NCN, bool XF32, bool ABF>
__global__ __launch_bounds__(256) void gemm_mfma_k(
    const void* __restrict__ Hv, const ushort* __restrict__ Wf,
    const float* __restrict__ bias, void* __restrict__ Av, ushort* __restrict__ Bt)
{
    gemm_body<NCS, NCN, XF32, ABF>(blockIdx.x, threadIdx.x, Hv, Wf, bias, Av, Bt);
}

// ---------------- pscatter (block-major pb) + fused layer-0 GEMM ----------------
// blocks [0,NBLKS): local hist + LDS scan; write pb into private region
// [blk*EPB,(blk+1)*EPB); write lofs[(bucket,blk)]; non-returning atomic btot.
// blocks [NBLKS, NBLKS+GEMM_BLOCKS): gemm0 (x -> Abf,Bt).
__global__ __launch_bounds__(256) void pscatter_gemm0_k(
    const int* __restrict__ src, const int* __restrict__ dst,
    int* __restrict__ pb, int* __restrict__ lofs, int* __restrict__ btot,
    const float* __restrict__ x, const ushort* __restrict__ wf0,
    const float* __restrict__ b0, ushort* __restrict__ Abf, ushort* __restrict__ Bt)
{
    __shared__ int h[NB];
    __shared__ int wc[NB];
    __shared__ int tsum[256];
    const int t = threadIdx.x;
    if (blockIdx.x >= NBLKS) {
        gemm_body<128, 128, true, true>(blockIdx.x - NBLKS, t, x, wf0, b0, Abf, Bt);
        return;
    }
    const int blk = blockIdx.x;
    const int e0 = blk * EPB;
    for (int i = t; i < NB; i += 256) h[i] = 0;
    __syncthreads();
    for (int e = e0 + t; e < e0 + EPB; e += 256)
        atomicAdd(&h[dst[e] >> BSH], 1);
    __syncthreads();
    int v[4];
    const int base4 = t * 4;
    #pragma unroll
    for (int i = 0; i < 4; ++i) {
        const int idx = base4 + i;
        v[i] = (idx < NB) ? h[idx] : 0;
    }
    const int s = v[0] + v[1] + v[2] + v[3];
    tsum[t] = s;
    __syncthreads();
    #pragma unroll
    for (int off = 1; off < 256; off <<= 1) {
        const int cur = tsum[t];
        const int y = (t >= off) ? tsum[t - off] : 0;
        __syncthreads();
        tsum[t] = cur + y;
        __syncthreads();
    }
    int run = tsum[t] - s;
    #pragma unroll
    for (int i = 0; i < 4; ++i) {
        const int idx = base4 + i;
        if (idx < NB) {
            wc[idx] = run;
            lofs[idx * NBLKS + blk] = run;
            if (v[i]) atomicAdd(&btot[idx], v[i]);   // non-returning: no serialization
        }
        run += v[i];
    }
    __syncthreads();
    for (int e = e0 + t; e < e0 + EPB; e += 256) {
        const int d = dst[e];
        const int pos = e0 + atomicAdd(&wc[d >> BSH], 1);
        pb[pos] = (src[e] << BSH) | (d & (BND - 1));
    }
}

// ---------------- bucket_place: one block per bucket ----------------
__global__ __launch_bounds__(256) void bucket_place_k(
    const int* __restrict__ btot, const int* __restrict__ lofs,
    const int* __restrict__ pb, int* __restrict__ row, int* __restrict__ esrc)
{
    __shared__ int cnt[BND], wc[BND], excl[BND], scan[BND];
    __shared__ int red[256];
    const int b = blockIdx.x;
    const int t = threadIdx.x;
    int part = 0;
    #pragma unroll
    for (int i = 0; i < 4; ++i) {
        const int idx = t * 4 + i;
        if (idx < b && idx < NB) part += btot[idx];
    }
    red[t] = part;
    if (t < BND) { cnt[t] = 0; wc[t] = 0; }
    __syncthreads();
    for (int off = 128; off > 0; off >>= 1) {
        if (t < off) red[t] += red[t + off];
        __syncthreads();
    }
    const int s0 = red[0];
    const int lo = lofs[b * NBLKS + t];
    const int lcount = ((b + 1 < NB) ? lofs[(b + 1) * NBLKS + t] : EPB) - lo;
    const int lstart = t * EPB + lo;
    for (int k = 0; k < lcount; ++k)
        atomicAdd(&cnt[pb[lstart + k] & (BND - 1)], 1);
    __syncthreads();
    if (t < BND) scan[t] = cnt[t];
    __syncthreads();
    for (int off = 1; off < BND; off <<= 1) {
        int nv = 0;
        if (t < BND) {
            nv = scan[t];
            if (t >= off) nv += scan[t - off];
        }
        __syncthreads();
        if (t < BND) scan[t] = nv;
        __syncthreads();
    }
    if (t < BND) {
        const int ex = scan[t] - cnt[t];
        excl[t] = ex;
        const int node = b * BND + t;
        if (node <= NN) row[node] = s0 + ex;   // node==NN -> row[NN]=NE
    }
    __syncthreads();
    for (int k = 0; k < lcount; ++k) {
        const int p = pb[lstart + k];
        const int dl = p & (BND - 1);
        const int pos = s0 + excl[dl] + atomicAdd(&wc[dl], 1);
        esrc[pos] = p >> BSH;
    }
}

// ---------------- aggregation (row-major, R8 proven) ----------------
// 128-wide: 2 nodes per wave (half-wave each, contiguous edges), uint2 loads.
__global__ __launch_bounds__(256) void agg128_k(
    const int* __restrict__ row, const int* __restrict__ esrc,
    const ushort* __restrict__ Bt, const ushort* __restrict__ Abf, ushort* __restrict__ Hb)
{
    const int w = (blockIdx.x * 256 + threadIdx.x) >> 6;
    const int half = (threadIdx.x >> 5) & 1;
    const int ln = threadIdx.x & 31;
    const int node = w * 2 + half;
    if (node >= NN) return;
    const int e0 = row[node];
    const int e1 = row[node + 1];
    const uint2* B = (const uint2*)Bt;          // row = 32 x uint2 (256B)
    float a0 = 0.f, a1 = 0.f, a2 = 0.f, a3 = 0.f;
    int e = e0;
    for (; e + 8 <= e1; e += 8) {
        int s[8];
        #pragma unroll
        for (int j = 0; j < 8; ++j) s[j] = esrc[e + j];
        uint2 v[8];
        #pragma unroll
        for (int j = 0; j < 8; ++j) v[j] = B[(size_t)s[j] * 32 + ln];
        #pragma unroll
        for (int j = 0; j < 8; ++j) {
            a0 += bf_lo(v[j].x); a1 += bf_hi(v[j].x);
            a2 += bf_lo(v[j].y); a3 += bf_hi(v[j].y);
        }
    }
    for (; e + 2 <= e1; e += 2) {
        const int s0 = esrc[e], s1 = esrc[e + 1];
        const uint2 v0 = B[(size_t)s0 * 32 + ln];
        const uint2 v1 = B[(size_t)s1 * 32 + ln];
        a0 += bf_lo(v0.x) + bf_lo(v1.x); a1 += bf_hi(v0.x) + bf_hi(v1.x);
        a2 += bf_lo(v0.y) + bf_lo(v1.y); a3 += bf_hi(v0.y) + bf_hi(v1.y);
    }
    if (e < e1) {
        const uint2 v = B[(size_t)esrc[e] * 32 + ln];
        a0 += bf_lo(v.x); a1 += bf_hi(v.x);
        a2 += bf_lo(v.y); a3 += bf_hi(v.y);
    }
    const int deg = e1 - e0;
    const float invd = (deg > 0) ? 1.0f / (float)deg : 0.0f;
    const uint2 aw = ((const uint2*)Abf)[(size_t)node * 32 + ln];
    const float v0 = fmaxf(bf_lo(aw.x) + a0 * invd, 0.f);
    const float v1 = fmaxf(bf_hi(aw.x) + a1 * invd, 0.f);
    const float v2 = fmaxf(bf_lo(aw.y) + a2 * invd, 0.f);
    const float v3 = fmaxf(bf_hi(aw.y) + a3 * invd, 0.f);
    uint2 o;
    o.x = (uint)f2bf(v0) | ((uint)f2bf(v1) << 16);
    o.y = (uint)f2bf(v2) | ((uint)f2bf(v3) << 16);
    ((uint2*)Hb)[(size_t)node * 32 + ln] = o;
}

// 64-wide: 16 lanes/node, uint2 loads. out[node] += mean(Bt64[src]), fp32, no relu.
__global__ __launch_bounds__(256) void agg64_k(
    const int* __restrict__ row, const int* __restrict__ esrc,
    const ushort* __restrict__ Bt, float* __restrict__ out)
{
    const int node = (blockIdx.x * 256 + threadIdx.x) >> 4;
    const int ln = threadIdx.x & 15;
    if (node >= NN) return;
    const int e0 = row[node];
    const int e1 = row[node + 1];
    const uint2* B = (const uint2*)Bt;          // row = 16 x uint2 (128B)
    float a0 = 0.f, a1 = 0.f, a2 = 0.f, a3 = 0.f;
    int e = e0;
    for (; e + 8 <= e1; e += 8) {
        int s[8];
        #pragma unroll
        for (int j = 0; j < 8; ++j) s[j] = esrc[e + j];
        uint2 v[8];
        #pragma unroll
        for (int j = 0; j < 8; ++j) v[j] = B[(size_t)s[j] * 16 + ln];
        #pragma unroll
        for (int j = 0; j < 8; ++j) {
            a0 += bf_lo(v[j].x); a1 += bf_hi(v[j].x);
            a2 += bf_lo(v[j].y); a3 += bf_hi(v[j].y);
        }
    }
    for (; e + 2 <= e1; e += 2) {
        const int s0 = esrc[e], s1 = esrc[e + 1];
        const uint2 v0 = B[(size_t)s0 * 16 + ln];
        const uint2 v1 = B[(size_t)s1 * 16 + ln];
        a0 += bf_lo(v0.x) + bf_lo(v1.x); a1 += bf_hi(v0.x) + bf_hi(v1.x);
        a2 += bf_lo(v0.y) + bf_lo(v1.y); a3 += bf_hi(v0.y) + bf_hi(v1.y);
    }
    if (e < e1) {
        const uint2 v = B[(size_t)esrc[e] * 16 + ln];
        a0 += bf_lo(v.x); a1 += bf_hi(v.x);
        a2 += bf_lo(v.y); a3 += bf_hi(v.y);
    }
    const int deg = e1 - e0;
    const float invd = (deg > 0) ? 1.0f / (float)deg : 0.0f;
    float4* op = (float4*)(out + (size_t)node * 64 + ln * 4);
    float4 o = *op;
    o.x += a0 * invd; o.y += a1 * invd;
    o.z += a2 * invd; o.w += a3 * invd;
    *op = o;
}

// ---------------- fp32 fallback path (small workspace) ----------------
__device__ inline float4 relu4f(float4 v) {
    v.x = fmaxf(v.x, 0.f); v.y = fmaxf(v.y, 0.f);
    v.z = fmaxf(v.z, 0.f); v.w = fmaxf(v.w, 0.f);
    return v;
}
template<int NCOL, bool RELU_IN, bool BIAS>
__global__ __launch_bounds__(256) void gemm_k(
    const float* in, const float* __restrict__ W,
    const float* __restrict__ bias, float* out)
{
    constexpr int K = 128;
    constexpr int QUADS = NCOL / 4;
    constexpr int G = 256 / QUADS;
    constexpr int RPT = 32 / G;
    __shared__ float Wlds[K * NCOL];
    {
        const float4* Wg = reinterpret_cast<const float4*>(W);
        float4* Wl = reinterpret_cast<float4*>(Wlds);
        #pragma unroll
        for (int i = 0; i < K * NCOL / 4 / 256; ++i)
            Wl[threadIdx.x + i * 256] = Wg[threadIdx.x + i * 256];
    }
    __syncthreads();
    const int tx = threadIdx.x % QUADS;
    const int ty = threadIdx.x / QUADS;
    const int row0 = blockIdx.x * 32;
    const float* rp[RPT];
    #pragma unroll
    for (int i = 0; i < RPT; ++i) rp[i] = in + (size_t)(row0 + ty + i * G) * K;
    float acc[RPT][4];
    #pragma unroll
    for (int i = 0; i < RPT; ++i) acc[i][0] = acc[i][1] = acc[i][2] = acc[i][3] = 0.f;
    #pragma unroll 2
    for (int kc = 0; kc < K; kc += 4) {
        float4 h4[RPT];
        #pragma unroll
        for (int i = 0; i < RPT; ++i) {
            h4[i] = *reinterpret_cast<const float4*>(rp[i] + kc);
            if (RELU_IN) h4[i] = relu4f(h4[i]);
        }
        #pragma unroll
        for (int kk = 0; kk < 4; ++kk) {
            const float4 w4 = *reinterpret_cast<const float4*>(&Wlds[(kc + kk) * NCOL + tx * 4]);
            #pragma unroll
            for (int i = 0; i < RPT; ++i) {
                const float hv = (&h4[i].x)[kk];
                acc[i][0] = fmaf(hv, w4.x, acc[i][0]);
                acc[i][1] = fmaf(hv, w4.y, acc[i][1]);
                acc[i][2] = fmaf(hv, w4.z, acc[i][2]);
                acc[i][3] = fmaf(hv, w4.w, acc[i][3]);
            }
        }
    }
    float4 b4 = make_float4(0.f, 0.f, 0.f, 0.f);
    if (BIAS) b4 = *reinterpret_cast<const float4*>(&bias[tx * 4]);
    #pragma unroll
    for (int i = 0; i < RPT; ++i) {
        const int r = row0 + ty + i * G;
        float4 o;
        o.x = acc[i][0] + b4.x; o.y = acc[i][1] + b4.y;
        o.z = acc[i][2] + b4.z; o.w = acc[i][3] + b4.w;
        *reinterpret_cast<float4*>(&out[(size_t)r * NCOL + tx * 4]) = o;
    }
}
__global__ void deg_k(const int* __restrict__ dst, float* __restrict__ deg, int E) {
    const int i = blockIdx.x * blockDim.x + threadIdx.x;
    if (i < E) atomicAdd(&deg[dst[i]], 1.0f);
}
__global__ void inv_k(float* deg, int n) {
    const int i = blockIdx.x * blockDim.x + threadIdx.x;
    if (i < n) deg[i] = 1.0f / fmaxf(deg[i], 1.0f);
}
__global__ __launch_bounds__(256) void scatter128_k(
    const int* __restrict__ src, const int* __restrict__ dst,
    const float* __restrict__ inv, const float* __restrict__ B, float* A, int E) {
    const int lane = threadIdx.x & 63;
    int w = (blockIdx.x * 256 + threadIdx.x) >> 6;
    const int nw = (gridDim.x * 256) >> 6;
    for (int e = w; e < E; e += nw) {
        const int s = src[e], d = dst[e];
        const float sc = inv[d];
        const float2 v = *reinterpret_cast<const float2*>(&B[(size_t)s * 128 + lane * 2]);
        atomicAdd(&A[(size_t)d * 128 + lane * 2    ], v.x * sc);
        atomicAdd(&A[(size_t)d * 128 + lane * 2 + 1], v.y * sc);
    }
}
__global__ __launch_bounds__(256) void scatter64_k(
    const int* __restrict__ src, const int* __restrict__ dst,
    const float* __restrict__ inv, const float* __restrict__ B, float* A, int E) {
    const int lane = threadIdx.x & 63;
    int w = (blockIdx.x * 256 + threadIdx.x) >> 6;
    const int nw = (gridDim.x * 256) >> 6;
    for (int e = w; e < E; e += nw) {
        const int s = src[e], d = dst[e];
        atomicAdd(&A[(size_t)d * 64 + lane], B[(size_t)s * 64 + lane] * inv[d]);
    }
}

extern "C" void kernel_launch(void* const* d_in, const int* in_sizes, int n_in,
                              void* d_out, int out_size, void* d_ws, size_t ws_size,
                              hipStream_t stream) {
    const float* x   = (const float*)d_in[0];
    const int*   src = (const int*)  d_in[1];
    const int*   dst = (const int*)  d_in[2];
    const float* ws0 = (const float*)d_in[3];
    const float* wn0 = (const float*)d_in[4];
    const float* b0  = (const float*)d_in[5];
    const float* ws1 = (const float*)d_in[6];
    const float* wn1 = (const float*)d_in[7];
    const float* b1  = (const float*)d_in[8];
    const float* ws2 = (const float*)d_in[9];
    const float* wn2 = (const float*)d_in[10];
    const float* b2  = (const float*)d_in[11];
    float* out = (float*)d_out;

    // workspace layout (byte offsets, no aliasing)
    const size_t O_BTOT = 4096;       // NB*4
    const size_t O_ROW  = 16384;      // (NN+1)*4
    const size_t O_WF0  = 417792;     // 65536
    const size_t O_WF1  = 483328;     // 65536
    const size_t O_WF2  = 548864;     // 32768
    const size_t O_ESRC = 581632;     // 6,400,000
    const size_t O_PB   = 6983680;    // 6,400,000
    const size_t O_LOFS = 13383680;   // 800,768
    const size_t O_A    = 14185472;   // 25,600,000 (bf16 row-major)
    const size_t O_BT   = 39785472;   // 25,600,000
    const size_t O_HB   = 65385472;   // 25,600,000
    const size_t NEED   = 90985472;

    if (ws_size >= NEED) {
        int*    btot = (int*)   ((char*)d_ws + O_BTOT);
        int*    row  = (int*)   ((char*)d_ws + O_ROW);
        ushort* wf0  = (ushort*)((char*)d_ws + O_WF0);
        ushort* wf1  = (ushort*)((char*)d_ws + O_WF1);
        ushort* wf2  = (ushort*)((char*)d_ws + O_WF2);
        int*    esrc = (int*)   ((char*)d_ws + O_ESRC);
        int*    pb   = (int*)   ((char*)d_ws + O_PB);
        int*    lofs = (int*)   ((char*)d_ws + O_LOFS);
        ushort* Abf  = (ushort*)((char*)d_ws + O_A);
        ushort* Bt   = (ushort*)((char*)d_ws + O_BT);
        ushort* Hb   = (ushort*)((char*)d_ws + O_HB);

        hipMemsetAsync(btot, 0, NB * sizeof(int), stream);
        pack_k<<<40, 256, 0, stream>>>(ws0, wn0, wf0, ws1, wn1, wf1, ws2, wn2, wf2);
        pscatter_gemm0_k<<<NBLKS + GEMM_BLOCKS, 256, 0, stream>>>(
            src, dst, pb, lofs, btot, x, wf0, b0, Abf, Bt);
        bucket_place_k<<<NB, 256, 0, stream>>>(btot, lofs, pb, row, esrc);

        const int AGG128_BLOCKS = (NN / 2 + 3) / 4;   // 12500 (2 nodes/wave)
        const int A64B = (NN + 15) / 16;              // 6250 (16 lanes/node)

        // layer 0 (gemm0 done in fused launch)
        agg128_k<<<AGG128_BLOCKS, 256, 0, stream>>>(row, esrc, Bt, Abf, Hb);
        // layer 1
        gemm_mfma_k<128, 128, false, true ><<<GEMM_BLOCKS, 256, 0, stream>>>(Hb, wf1, b1, Abf, Bt);
        agg128_k<<<AGG128_BLOCKS, 256, 0, stream>>>(row, esrc, Bt, Abf, Hb);
        // layer 2 (self fp32 straight to d_out; then in-place mean add)
        gemm_mfma_k<64, 64, false, false><<<GEMM_BLOCKS, 256, 0, stream>>>(Hb, wf2, b2, out, Bt);
        agg64_k<<<A64B, 256, 0, stream>>>(row, esrc, Bt, out);
    } else {
        // fp32 atomic fallback
        float* inv = (float*)d_ws;
        float* H0  = (float*)((char*)d_ws + (1u << 20));
        float* Bf  = H0 + (size_t)NN * 128;
        const int GB = NN / 32;
        const int SC_BLOCKS = 4096;
        hipMemsetAsync(inv, 0, NN * sizeof(float), stream);
        deg_k<<<(NE + 255) / 256, 256, 0, stream>>>(dst, inv, NE);
        inv_k<<<(NN + 255) / 256, 256, 0, stream>>>(inv, NN);
        gemm_k<128, false, false><<<GB, 256, 0, stream>>>(x, wn0, nullptr, Bf);
        gemm_k<128, false, true ><<<GB, 256, 0, stream>>>(x, ws0, b0, H0);
        scatter128_k<<<SC_BLOCKS, 256, 0, stream>>>(src, dst, inv, Bf, H0, NE);
        gemm_k<128, true, false><<<GB, 256, 0, stream>>>(H0, wn1, nullptr, Bf);
        gemm_k<128, true, true ><<<GB, 256, 0, stream>>>(H0, ws1, b1, H0);
        scatter128_k<<<SC_BLOCKS, 256, 0, stream>>>(src, dst, inv, Bf, H0, NE);
        gemm_k<64, true, false><<<GB, 256, 0, stream>>>(H0, wn2, nullptr, Bf);
        gemm_k<64, true, true ><<<GB, 256, 0, stream>>>(H0, ws2, b2, out);
        scatter64_k<<<SC_BLOCKS, 256, 0, stream>>>(src, dst, inv, Bf, out, NE);
    }
}